// Round 19
// baseline (143.184 us; speedup 1.0000x reference)
//
#include <hip/hip_runtime.h>
#include <stdint.h>

// Problem constants
#define NUM_C 1000
#define NB    4096
#define NCOL  9192          // NB + NUM_C + NO
#define NPAD  9216          // 576 row-tiles of 16
#define DK    512
#define BM    128
#define BN    256
#define INV_T 10.0f

typedef __attribute__((ext_vector_type(4))) float f32x4;
typedef __attribute__((ext_vector_type(8))) int  v8i;

// workspace layout (bytes)
// fall: MX fragment-linear fp8 [tile=576][kb=4][lane=64][32B] = 4,718,592 B
//   thread (t,kb,lane): row = t*16+(lane&15), k = kb*128 + (lane>>4)*32 .. +31
#define OFF_FALL  0u
#define OFF_CNT   4718592u           // uint[1024] final hist (targets+pseudo)
#define OFF_CNTT  4722688u           // uint[1024] final hist (targets only)
#define OFF_S     4726784u           // float[4096]
#define OFF_P     4743168u           // float[4096]  (contiguous after S)

#define SCL 0x7F7F7F7Fu              // e8m0 1.0 in every byte

__device__ __forceinline__ void async16(const void* g, void* l) {
  __builtin_amdgcn_global_load_lds((const __attribute__((address_space(1))) void*)g,
                                   (__attribute__((address_space(3))) void*)l,
                                   16, 0, 0);
}

// f32 -> e4m3fn (OCP), software RNE fallback
__device__ __forceinline__ unsigned sw_e4m3(float x) {
  float ax = fabsf(x);
  unsigned s = (__float_as_uint(x) >> 24) & 0x80u;
  if (ax < 0.015625f) {
    int n = (int)rintf(ax * 512.0f);
    if (n >= 8) return s | 0x08u;
    return s | (unsigned)n;
  }
  if (ax >= 448.0f) return s | 0x7Eu;
  unsigned u = __float_as_uint(ax);
  int ee = (int)(u >> 23) - 127;
  float scale = __uint_as_float((unsigned)(3 - ee + 127) << 23);
  int qv = (int)rintf(ax * scale);
  if (qv == 16) { ee++; qv = 8; }
  return s | (unsigned)(((ee + 7) << 3) | (qv - 8));
}

template <bool HI>
__device__ __forceinline__ int cvt2(float a, float b, int old) {
#if __has_builtin(__builtin_amdgcn_cvt_pk_fp8_f32)
  return __builtin_amdgcn_cvt_pk_fp8_f32(a, b, old, HI);
#else
  unsigned pk = sw_e4m3(a) | (sw_e4m3(b) << 8);
  return HI ? (int)(((unsigned)old & 0x0000FFFFu) | (pk << 16))
            : (int)(((unsigned)old & 0xFFFF0000u) | pk);
#endif
}

// Build fall in MX fragment-linear layout: one thread = one 32B K=128 operand slice.
// blocks 0..15: LDS partial histograms -> global atomicAdd into cnt/cntT (pre-zeroed)
// blocks 16..47: zero S/P
__global__ __launch_bounds__(256) void prep_k(const float* __restrict__ centers,
                                              const float* __restrict__ feats,
                                              const float* __restrict__ ood,
                                              const int* __restrict__ targets,
                                              const int* __restrict__ pseudo,
                                              unsigned char* __restrict__ fall,
                                              unsigned* __restrict__ cnt,
                                              unsigned* __restrict__ cntT,
                                              float* __restrict__ SP) {
  __shared__ unsigned hc[1024];
  __shared__ unsigned hct[1024];
  const int tid = threadIdx.x;

  int idx  = blockIdx.x * 256 + tid;      // 0 .. 147455
  int lane = idx & 63;
  int kb   = (idx >> 6) & 3;
  int t    = idx >> 8;
  int row  = t * 16 + (lane & 15);
  int k0   = kb * 128 + (lane >> 4) * 32;

  const float* src = nullptr;
  if (row < NB)              src = feats   + (size_t)row * DK;
  else if (row < NB + NUM_C) src = centers + (size_t)(row - NB) * DK;
  else if (row < NCOL)       src = ood     + (size_t)(row - NB - NUM_C) * DK;
  uint4 o0 = make_uint4(0u, 0u, 0u, 0u), o1 = o0;
  if (src) {
    const float4* s4 = (const float4*)(src + k0);
    unsigned w[8];
#pragma unroll
    for (int g = 0; g < 8; g += 2) {
      float4 va = s4[g], vb = s4[g + 1];
      int p = 0;
      p = cvt2<false>(va.x, va.y, p); p = cvt2<true>(va.z, va.w, p); w[g] = (unsigned)p;
      p = 0;
      p = cvt2<false>(vb.x, vb.y, p); p = cvt2<true>(vb.z, vb.w, p); w[g + 1] = (unsigned)p;
    }
    o0 = make_uint4(w[0], w[1], w[2], w[3]);
    o1 = make_uint4(w[4], w[5], w[6], w[7]);
  }
  uint4* dst = (uint4*)(fall + (size_t)idx * 32);
  dst[0] = o0;
  dst[1] = o1;

  if (blockIdx.x < 16) {
    for (int kk = tid; kk < 1024; kk += 256) { hc[kk] = 0u; hct[kk] = 0u; }
    __syncthreads();
    int i = blockIdx.x * 256 + tid;      // 0..4095
    int tt = targets[i];
    atomicAdd(&hc[tt], 1u);
    atomicAdd(&hct[tt], 1u);
    atomicAdd(&hc[pseudo[i]], 1u);
    __syncthreads();
    for (int kk = tid; kk < 1024; kk += 256) {
      unsigned c = hc[kk], ct = hct[kk];
      if (c)  atomicAdd(&cnt[kk], c);
      if (ct) atomicAdd(&cntT[kk], ct);
    }
  } else if (blockIdx.x < 48) {
    SP[(blockIdx.x - 16) * 256 + tid] = 0.0f;   // zeros S[4096] then P[4096]
  }
}

// Fused MX-fp8 GEMM 128x256: A tile (64 KB) resident in LDS; B direct from
// global as 32B K=128 operands, two 4-tile register banks rotated at half-kb
// granularity. mfma_scale 16x16x128 with unit scales (2x fp8 rate). Zero
// K-loop barriers.
__global__ __launch_bounds__(256, 2) void gemm_fused(const unsigned char* __restrict__ fall,
                                                     const int* __restrict__ targets,
                                                     const int* __restrict__ pseudo,
                                                     const unsigned* __restrict__ cnt,
                                                     float* __restrict__ Sacc,
                                                     float* __restrict__ Pacc) {
  __shared__ unsigned char Alds[65536];   // block's A: tiles mTile*8..+7, fall-layout copy
  __shared__ int    sLbl[BN];
  __shared__ float  sRw0[BN];
  __shared__ float  sRw1[BN];
  __shared__ int    sTgt[BM];

  const int tid   = threadIdx.x;
  const int nTile = blockIdx.x;   // 36
  const int mTile = blockIdx.y;   // 32
  const int lane  = tid & 63;
  const int wv    = tid >> 6;     // wave 0..3
  const int wm    = wv >> 1;      // row half (tiles wm*4..+3)
  const int wn    = wv & 1;       // col half (tiles wn*8..+7)
  const int q     = lane >> 4;    // k-quad
  const int cIdx  = lane & 15;

  // prologue: copy A (contiguous 64 KB of fall) into LDS via DMA
  {
    const unsigned char* aSrc = fall + (size_t)(mTile * 8) * 8192;
#pragma unroll
    for (int i = 0; i < 16; i++)
      async16(aSrc + (i * 256 + tid) * 16, &Alds[(i * 256 + tid) * 16]);
  }

  // per-column tables (lbl, 1/w, 1/(w-1)); per-row targets. w = 1 + cnt[tac].
  {
    int j = nTile * BN + tid;
    int lbl, tac;
    if (j >= NCOL)         { lbl = -1; tac = -1; }
    else if (j < NB)       { tac = targets[j]; lbl = tac; }
    else if (j < NB+NUM_C) { tac = j - NB;     lbl = tac; }
    else                   { tac = pseudo[j - NB - NUM_C]; lbl = NUM_C; }
    sLbl[tid] = lbl;
    if (tac >= 0) {
      float w = (float)(1u + cnt[tac]);
      sRw0[tid] = 1.0f / w;
      sRw1[tid] = 1.0f / (w - 1.0f);  // only selected when a positive exists => w>=2
    } else {
      sRw0[tid] = 0.f;
      sRw1[tid] = 0.f;
    }
    if (tid < BM) sTgt[tid] = targets[mTile * BM + tid];
  }

  f32x4 acc[4][8];
#pragma unroll
  for (int mi = 0; mi < 4; mi++)
#pragma unroll
    for (int ni = 0; ni < 8; ni++)
      acc[mi][ni] = (f32x4){0.f, 0.f, 0.f, 0.f};

  // B base: tile (nTile*16 + wn*8 + ni) at fall + tile*8192 + kb*2048 + lane*32
  const unsigned char* bBase = fall + (size_t)(nTile * 16 + wn * 8) * 8192 + lane * 32;
  // A LDS base for this wave: tile (wm*4+mi) at Alds + tile*8192 + kb*2048 + lane*32
  const unsigned aOff = (unsigned)(wm * 4) * 8192u + (unsigned)lane * 32u;

  v8i bk0[4], bk1[4];
#pragma unroll
  for (int tt = 0; tt < 4; tt++) bk0[tt] = *(const v8i*)(bBase + (size_t)tt * 8192);        // kb0, g0
#pragma unroll
  for (int tt = 0; tt < 4; tt++) bk1[tt] = *(const v8i*)(bBase + (size_t)(4 + tt) * 8192);  // kb0, g1

  __syncthreads();   // A landed (vmcnt drain) + tables ready; only barrier

  v8i af[4];
#pragma unroll
  for (int h = 0; h < 8; h++) {
    const int kb = h >> 1;
    const int g  = h & 1;
    if (g == 0) {
#pragma unroll
      for (int mi = 0; mi < 4; mi++)
        af[mi] = *(const v8i*)&Alds[aOff + mi * 8192 + kb * 2048];
    }
#pragma unroll
    for (int mi = 0; mi < 4; mi++)
#pragma unroll
      for (int tt = 0; tt < 4; tt++) {
        if (g == 0)
          acc[mi][tt] = __builtin_amdgcn_mfma_scale_f32_16x16x128_f8f6f4(
              af[mi], bk0[tt], acc[mi][tt], 0, 0, 0, (int)SCL, 0, (int)SCL);
        else
          acc[mi][4 + tt] = __builtin_amdgcn_mfma_scale_f32_16x16x128_f8f6f4(
              af[mi], bk1[tt], acc[mi][4 + tt], 0, 0, 0, (int)SCL, 0, (int)SCL);
      }
    if (h + 2 < 8) {   // refill the bank just consumed with kb = (h+2)>>1
      const int nkb = (h + 2) >> 1;
#pragma unroll
      for (int tt = 0; tt < 4; tt++) {
        if (g == 0) bk0[tt] = *(const v8i*)(bBase + (size_t)tt * 8192 + nkb * 2048);
        else        bk1[tt] = *(const v8i*)(bBase + (size_t)(4 + tt) * 8192 + nkb * 2048);
      }
    }
  }

  // Epilogue: l = acc*10; S += exp(l-10) * (diag?0 : pos?1/(w-1) : 1/w); P += pos?l:0
  float vS[16], vP[16];
#pragma unroll
  for (int s = 0; s < 16; s++) { vS[s] = 0.f; vP[s] = 0.f; }

#pragma unroll
  for (int ni = 0; ni < 8; ni++) {
    int jloc = wn * 128 + ni * 16 + cIdx;
    int j    = nTile * BN + jloc;
    int lblj = sLbl[jloc];
    float rw0 = sRw0[jloc], rw1 = sRw1[jloc];
#pragma unroll
    for (int mi = 0; mi < 4; mi++) {
      f32x4 a = acc[mi][ni];
#pragma unroll
      for (int r = 0; r < 4; r++) {
        int iloc = wm * 64 + mi * 16 + q * 4 + r;
        int i    = mTile * BM + iloc;
        int ti   = sTgt[iloc];
        float l  = a[r] * INV_T;
        bool diag = (j == i);
        bool pos  = (lblj == ti) && !diag;
        float rw  = diag ? 0.0f : (pos ? rw1 : rw0);
        float e   = __expf(l - 10.0f) * rw;
        vS[mi * 4 + r] += e;
        vP[mi * 4 + r] += pos ? l : 0.0f;
      }
    }
  }

  // fully-static value-halving butterfly over the 16 cIdx lanes (15 shuffle pairs)
#define RED_STEP(m, s, h)                                        \
  {                                                              \
    float sendS = (cIdx & (m)) ? vS[(s)] : vS[(s) + (h)];        \
    float sendP = (cIdx & (m)) ? vP[(s)] : vP[(s) + (h)];        \
    float rS = __shfl_xor(sendS, (m), 64);                       \
    float rP = __shfl_xor(sendP, (m), 64);                       \
    vS[(s)] = ((cIdx & (m)) ? vS[(s) + (h)] : vS[(s)]) + rS;     \
    vP[(s)] = ((cIdx & (m)) ? vP[(s) + (h)] : vP[(s)]) + rP;     \
  }
  RED_STEP(8, 0, 8) RED_STEP(8, 1, 8) RED_STEP(8, 2, 8) RED_STEP(8, 3, 8)
  RED_STEP(8, 4, 8) RED_STEP(8, 5, 8) RED_STEP(8, 6, 8) RED_STEP(8, 7, 8)
  RED_STEP(4, 0, 4) RED_STEP(4, 1, 4) RED_STEP(4, 2, 4) RED_STEP(4, 3, 4)
  RED_STEP(2, 0, 2) RED_STEP(2, 1, 2)
  RED_STEP(1, 0, 1)
#undef RED_STEP

  {
    int rowLoc = wm * 64 + (cIdx >> 2) * 16 + q * 4 + (cIdx & 3);
    int i = mTile * BM + rowLoc;
    atomicAdd(&Sacc[i], vS[0]);
    atomicAdd(&Pacc[i], vP[0]);
  }
}

// loss = -mean( P/npos - 10 - log S );  npos_i = cntT[targets[i]]
__global__ __launch_bounds__(256) void finalize_k(const float* __restrict__ S,
                                                  const float* __restrict__ P,
                                                  const int* __restrict__ targets,
                                                  const unsigned* __restrict__ cntT,
                                                  float* __restrict__ out) {
  __shared__ unsigned ct[1024];
  __shared__ float red[4];
  int tid = threadIdx.x;
  for (int k = tid; k < 1024; k += 256) ct[k] = cntT[k];
  __syncthreads();
  float local = 0.f;
  for (int i = tid; i < NB; i += 256) {
    float npos = (float)ct[targets[i]];
    local += P[i] / npos - INV_T - __logf(S[i]);
  }
  for (int m = 1; m < 64; m <<= 1) local += __shfl_xor(local, m, 64);
  if ((tid & 63) == 0) red[tid >> 6] = local;
  __syncthreads();
  if (tid == 0) {
    float t = red[0] + red[1] + red[2] + red[3];
    out[0] = -t / (float)NB;
  }
}

extern "C" void kernel_launch(void* const* d_in, const int* in_sizes, int n_in,
                              void* d_out, int out_size, void* d_ws, size_t ws_size,
                              hipStream_t stream) {
  const float* centers = (const float*)d_in[0];   // [1000][512] f32
  const float* feats   = (const float*)d_in[1];   // [4096][512] f32
  const int*   targets = (const int*)d_in[2];     // [4096] i32
  const float* ood     = (const float*)d_in[3];   // [4096][512] f32
  const int*   pseudo  = (const int*)d_in[4];     // [4096] i32

  char* ws = (char*)d_ws;
  unsigned char* fall = (unsigned char*)(ws + OFF_FALL);
  unsigned* cnt   = (unsigned*)(ws + OFF_CNT);
  unsigned* cntT  = (unsigned*)(ws + OFF_CNTT);
  float*    Sacc  = (float*)(ws + OFF_S);
  float*    Pacc  = (float*)(ws + OFF_P);

  hipMemsetAsync(ws + OFF_CNT, 0, 8192, stream);   // zero cnt + cntT
  prep_k<<<dim3(576), 256, 0, stream>>>(centers, feats, ood, targets, pseudo,
                                        fall, cnt, cntT, Sacc);
  gemm_fused<<<dim3(NPAD / BN, NB / BM), 256, 0, stream>>>(fall, targets, pseudo, cnt, Sacc, Pacc);
  finalize_k<<<1, 256, 0, stream>>>(Sacc, Pacc, targets, cntT, (float*)d_out);
}

// Round 20
// 119.901 us; speedup vs baseline: 1.1942x; 1.1942x over previous
//
#include <hip/hip_runtime.h>
#include <stdint.h>

// Problem constants
#define NUM_C 1000
#define NB    4096
#define NCOL  9192          // NB + NUM_C + NO
#define NPAD  9216          // 576 row-tiles of 16
#define DK    512
#define BM    128
#define BN    256
#define INV_T 10.0f

typedef __attribute__((ext_vector_type(4))) float f32x4;

// workspace layout (bytes)
// fall: paired fragment-linear fp8 [tile=576][kp=8][lane=64][16B] = 4,718,592 B
#define OFF_FALL  0u
#define OFF_CNT   4718592u           // uint[1024] final hist (targets+pseudo)
#define OFF_CNTT  4722688u           // uint[1024] final hist (targets only)
#define OFF_S     4726784u           // float[4096]
#define OFF_P     4743168u           // float[4096]  (contiguous after S)

__device__ __forceinline__ void async16(const void* g, void* l) {
  __builtin_amdgcn_global_load_lds((const __attribute__((address_space(1))) void*)g,
                                   (__attribute__((address_space(3))) void*)l,
                                   16, 0, 0);
}

// f32 -> e4m3fn (OCP), software RNE fallback
__device__ __forceinline__ unsigned sw_e4m3(float x) {
  float ax = fabsf(x);
  unsigned s = (__float_as_uint(x) >> 24) & 0x80u;
  if (ax < 0.015625f) {
    int n = (int)rintf(ax * 512.0f);
    if (n >= 8) return s | 0x08u;
    return s | (unsigned)n;
  }
  if (ax >= 448.0f) return s | 0x7Eu;
  unsigned u = __float_as_uint(ax);
  int ee = (int)(u >> 23) - 127;
  float scale = __uint_as_float((unsigned)(3 - ee + 127) << 23);
  int qv = (int)rintf(ax * scale);
  if (qv == 16) { ee++; qv = 8; }
  return s | (unsigned)(((ee + 7) << 3) | (qv - 8));
}

template <bool HI>
__device__ __forceinline__ int cvt2(float a, float b, int old) {
#if __has_builtin(__builtin_amdgcn_cvt_pk_fp8_f32)
  return __builtin_amdgcn_cvt_pk_fp8_f32(a, b, old, HI);
#else
  unsigned pk = sw_e4m3(a) | (sw_e4m3(b) << 8);
  return HI ? (int)(((unsigned)old & 0x0000FFFFu) | (pk << 16))
            : (int)(((unsigned)old & 0xFFFF0000u) | pk);
#endif
}

__device__ __forceinline__ long long mk_ll(unsigned lo, unsigned hi) {
  return (long long)(((unsigned long long)hi << 32) | lo);
}

// Build fall in paired fragment-linear layout: one thread = one 16B pair.
// blocks 0..15: LDS partial histograms -> global atomicAdd into cnt/cntT (pre-zeroed)
// blocks 16..47: zero S/P
__global__ __launch_bounds__(256) void prep_k(const float* __restrict__ centers,
                                              const float* __restrict__ feats,
                                              const float* __restrict__ ood,
                                              const int* __restrict__ targets,
                                              const int* __restrict__ pseudo,
                                              uint4* __restrict__ fall,
                                              unsigned* __restrict__ cnt,
                                              unsigned* __restrict__ cntT,
                                              float* __restrict__ SP) {
  __shared__ unsigned hc[1024];
  __shared__ unsigned hct[1024];
  const int tid = threadIdx.x;

  int idx  = blockIdx.x * 256 + tid;      // 0 .. 294911
  int lane = idx & 63;
  int kp   = (idx >> 6) & 7;
  int t    = idx >> 9;
  int row  = t * 16 + (lane & 15);
  int k0   = kp * 64 + (lane >> 4) * 8;   // frag s=0; s=1 at k0+32

  const float* src = nullptr;
  if (row < NB)              src = feats   + (size_t)row * DK;
  else if (row < NB + NUM_C) src = centers + (size_t)(row - NB) * DK;
  else if (row < NCOL)       src = ood     + (size_t)(row - NB - NUM_C) * DK;
  uint4 out = make_uint4(0u, 0u, 0u, 0u);
  if (src) {
    float4 v0 = *(const float4*)(src + k0);
    float4 v1 = *(const float4*)(src + k0 + 4);
    float4 v2 = *(const float4*)(src + k0 + 32);
    float4 v3 = *(const float4*)(src + k0 + 36);
    int p;
    p = 0; p = cvt2<false>(v0.x, v0.y, p); p = cvt2<true>(v0.z, v0.w, p); out.x = (unsigned)p;
    p = 0; p = cvt2<false>(v1.x, v1.y, p); p = cvt2<true>(v1.z, v1.w, p); out.y = (unsigned)p;
    p = 0; p = cvt2<false>(v2.x, v2.y, p); p = cvt2<true>(v2.z, v2.w, p); out.z = (unsigned)p;
    p = 0; p = cvt2<false>(v3.x, v3.y, p); p = cvt2<true>(v3.z, v3.w, p); out.w = (unsigned)p;
  }
  fall[idx] = out;

  if (blockIdx.x < 16) {
    for (int kk = tid; kk < 1024; kk += 256) { hc[kk] = 0u; hct[kk] = 0u; }
    __syncthreads();
    int i = blockIdx.x * 256 + tid;      // 0..4095
    int tt = targets[i];
    atomicAdd(&hc[tt], 1u);
    atomicAdd(&hct[tt], 1u);
    atomicAdd(&hc[pseudo[i]], 1u);
    __syncthreads();
    for (int kk = tid; kk < 1024; kk += 256) {
      unsigned c = hc[kk], ct = hct[kk];
      if (c)  atomicAdd(&cnt[kk], c);
      if (ct) atomicAdd(&cntT[kk], ct);
    }
  } else if (blockIdx.x < 48) {
    SP[(blockIdx.x - 16) * 256 + tid] = 0.0f;   // zeros S[4096] then P[4096]
  }
}

// Fused fp8 GEMM 128x256: A tile (64 KB) resident in LDS (one prologue copy),
// B direct from global as paired dwordx4 (2 k-slabs per load, ping-pong).
// Zero barriers in the K-loop. Per-column weight = single cnt load.
// Wave mapping 2x2 (64x128 each): B duplication across wave pairs is near-free
// (same-CU L1); per-wave MLP of 8 B-loads is what matters (r17 lesson).
// MX-scaled K=128 variant spills (r19 lesson) — K=32 operands are the fit.
__global__ __launch_bounds__(256, 2) void gemm_fused(const unsigned char* __restrict__ fall,
                                                     const int* __restrict__ targets,
                                                     const int* __restrict__ pseudo,
                                                     const unsigned* __restrict__ cnt,
                                                     float* __restrict__ Sacc,
                                                     float* __restrict__ Pacc) {
  __shared__ unsigned char Alds[65536];   // block's A: tiles mTile*8..+7, fall-layout copy
  __shared__ int    sLbl[BN];
  __shared__ float  sRw0[BN];
  __shared__ float  sRw1[BN];
  __shared__ int    sTgt[BM];

  const int tid   = threadIdx.x;
  const int nTile = blockIdx.x;   // 36
  const int mTile = blockIdx.y;   // 32
  const int lane  = tid & 63;
  const int wv    = tid >> 6;     // wave 0..3
  const int wm    = wv >> 1;      // row half (tiles wm*4..+3)
  const int wn    = wv & 1;       // col half (tiles wn*8..+7)
  const int q     = lane >> 4;    // k-quad
  const int cIdx  = lane & 15;

  // prologue: copy A (contiguous 64 KB of fall) into LDS via DMA
  {
    const unsigned char* aSrc = fall + (size_t)(mTile * 8) * 8192;
#pragma unroll
    for (int i = 0; i < 16; i++)
      async16(aSrc + (i * 256 + tid) * 16, &Alds[(i * 256 + tid) * 16]);
  }

  // per-column tables (lbl, 1/w, 1/(w-1)); per-row targets. w = 1 + cnt[tac].
  {
    int j = nTile * BN + tid;
    int lbl, tac;
    if (j >= NCOL)         { lbl = -1; tac = -1; }
    else if (j < NB)       { tac = targets[j]; lbl = tac; }
    else if (j < NB+NUM_C) { tac = j - NB;     lbl = tac; }
    else                   { tac = pseudo[j - NB - NUM_C]; lbl = NUM_C; }
    sLbl[tid] = lbl;
    if (tac >= 0) {
      float w = (float)(1u + cnt[tac]);
      sRw0[tid] = 1.0f / w;
      sRw1[tid] = 1.0f / (w - 1.0f);  // only selected when a positive exists => w>=2
    } else {
      sRw0[tid] = 0.f;
      sRw1[tid] = 0.f;
    }
    if (tid < BM) sTgt[tid] = targets[mTile * BM + tid];
  }

  f32x4 acc[4][8];
#pragma unroll
  for (int mi = 0; mi < 4; mi++)
#pragma unroll
    for (int ni = 0; ni < 8; ni++)
      acc[mi][ni] = (f32x4){0.f, 0.f, 0.f, 0.f};

  // B base: tile (nTile*16 + wn*8 + ni) at fall + tile*8192 + kp*1024 + lane*16
  const unsigned char* bBase = fall + (size_t)(nTile * 16 + wn * 8) * 8192 + lane * 16;
  // A LDS base for this wave: tile (wm*4+mi), same internal layout
  const unsigned aBase = (unsigned)(wm * 4) * 8192u + (unsigned)lane * 16u;

  uint4 bCur[8], bNxt[8];
#pragma unroll
  for (int ni = 0; ni < 8; ni++)
    bCur[ni] = *(const uint4*)(bBase + ni * 8192);

  __syncthreads();   // A landed (vmcnt drain) + tables ready; only barrier

#pragma unroll
  for (int kp = 0; kp < 8; kp++) {
    if (kp < 7) {
#pragma unroll
      for (int ni = 0; ni < 8; ni++)
        bNxt[ni] = *(const uint4*)(bBase + ni * 8192 + (kp + 1) * 1024);
    }
    long long af0[4], af1[4];
#pragma unroll
    for (int mi = 0; mi < 4; mi++) {
      af0[mi] = *(const long long*)&Alds[aBase + mi * 8192 + kp * 1024];
      af1[mi] = *(const long long*)&Alds[aBase + mi * 8192 + kp * 1024 + 8];
    }
#pragma unroll
    for (int mi = 0; mi < 4; mi++)
#pragma unroll
      for (int ni = 0; ni < 8; ni++)
        acc[mi][ni] = __builtin_amdgcn_mfma_f32_16x16x32_fp8_fp8(af0[mi], mk_ll(bCur[ni].x, bCur[ni].y), acc[mi][ni], 0, 0, 0);
#pragma unroll
    for (int mi = 0; mi < 4; mi++)
#pragma unroll
      for (int ni = 0; ni < 8; ni++)
        acc[mi][ni] = __builtin_amdgcn_mfma_f32_16x16x32_fp8_fp8(af1[mi], mk_ll(bCur[ni].z, bCur[ni].w), acc[mi][ni], 0, 0, 0);
    if (kp < 7) {
#pragma unroll
      for (int ni = 0; ni < 8; ni++) bCur[ni] = bNxt[ni];
    }
  }

  // Epilogue: l = acc*10; S += exp(l-10) * (diag?0 : pos?1/(w-1) : 1/w); P += pos?l:0
  float vS[16], vP[16];
#pragma unroll
  for (int s = 0; s < 16; s++) { vS[s] = 0.f; vP[s] = 0.f; }

#pragma unroll
  for (int ni = 0; ni < 8; ni++) {
    int jloc = wn * 128 + ni * 16 + cIdx;
    int j    = nTile * BN + jloc;
    int lblj = sLbl[jloc];
    float rw0 = sRw0[jloc], rw1 = sRw1[jloc];
#pragma unroll
    for (int mi = 0; mi < 4; mi++) {
      f32x4 a = acc[mi][ni];
#pragma unroll
      for (int r = 0; r < 4; r++) {
        int iloc = wm * 64 + mi * 16 + q * 4 + r;
        int i    = mTile * BM + iloc;
        int ti   = sTgt[iloc];
        float l  = a[r] * INV_T;
        bool diag = (j == i);
        bool pos  = (lblj == ti) && !diag;
        float rw  = diag ? 0.0f : (pos ? rw1 : rw0);
        float e   = __expf(l - 10.0f) * rw;
        vS[mi * 4 + r] += e;
        vP[mi * 4 + r] += pos ? l : 0.0f;
      }
    }
  }

  // fully-static value-halving butterfly over the 16 cIdx lanes (15 shuffle pairs)
#define RED_STEP(m, s, h)                                        \
  {                                                              \
    float sendS = (cIdx & (m)) ? vS[(s)] : vS[(s) + (h)];        \
    float sendP = (cIdx & (m)) ? vP[(s)] : vP[(s) + (h)];        \
    float rS = __shfl_xor(sendS, (m), 64);                       \
    float rP = __shfl_xor(sendP, (m), 64);                       \
    vS[(s)] = ((cIdx & (m)) ? vS[(s) + (h)] : vS[(s)]) + rS;     \
    vP[(s)] = ((cIdx & (m)) ? vP[(s) + (h)] : vP[(s)]) + rP;     \
  }
  RED_STEP(8, 0, 8) RED_STEP(8, 1, 8) RED_STEP(8, 2, 8) RED_STEP(8, 3, 8)
  RED_STEP(8, 4, 8) RED_STEP(8, 5, 8) RED_STEP(8, 6, 8) RED_STEP(8, 7, 8)
  RED_STEP(4, 0, 4) RED_STEP(4, 1, 4) RED_STEP(4, 2, 4) RED_STEP(4, 3, 4)
  RED_STEP(2, 0, 2) RED_STEP(2, 1, 2)
  RED_STEP(1, 0, 1)
#undef RED_STEP

  {
    int rowLoc = wm * 64 + (cIdx >> 2) * 16 + q * 4 + (cIdx & 3);
    int i = mTile * BM + rowLoc;
    atomicAdd(&Sacc[i], vS[0]);
    atomicAdd(&Pacc[i], vP[0]);
  }
}

// loss = -mean( P/npos - 10 - log S );  npos_i = cntT[targets[i]]
__global__ __launch_bounds__(256) void finalize_k(const float* __restrict__ S,
                                                  const float* __restrict__ P,
                                                  const int* __restrict__ targets,
                                                  const unsigned* __restrict__ cntT,
                                                  float* __restrict__ out) {
  __shared__ unsigned ct[1024];
  __shared__ float red[4];
  int tid = threadIdx.x;
  for (int k = tid; k < 1024; k += 256) ct[k] = cntT[k];
  __syncthreads();
  float local = 0.f;
  for (int i = tid; i < NB; i += 256) {
    float npos = (float)ct[targets[i]];
    local += P[i] / npos - INV_T - __logf(S[i]);
  }
  for (int m = 1; m < 64; m <<= 1) local += __shfl_xor(local, m, 64);
  if ((tid & 63) == 0) red[tid >> 6] = local;
  __syncthreads();
  if (tid == 0) {
    float t = red[0] + red[1] + red[2] + red[3];
    out[0] = -t / (float)NB;
  }
}

extern "C" void kernel_launch(void* const* d_in, const int* in_sizes, int n_in,
                              void* d_out, int out_size, void* d_ws, size_t ws_size,
                              hipStream_t stream) {
  const float* centers = (const float*)d_in[0];   // [1000][512] f32
  const float* feats   = (const float*)d_in[1];   // [4096][512] f32
  const int*   targets = (const int*)d_in[2];     // [4096] i32
  const float* ood     = (const float*)d_in[3];   // [4096][512] f32
  const int*   pseudo  = (const int*)d_in[4];     // [4096] i32

  char* ws = (char*)d_ws;
  uint4*    fall  = (uint4*)(ws + OFF_FALL);
  unsigned* cnt   = (unsigned*)(ws + OFF_CNT);
  unsigned* cntT  = (unsigned*)(ws + OFF_CNTT);
  float*    Sacc  = (float*)(ws + OFF_S);
  float*    Pacc  = (float*)(ws + OFF_P);

  hipMemsetAsync(ws + OFF_CNT, 0, 8192, stream);   // zero cnt + cntT
  prep_k<<<dim3((NPAD * 32) / 256), 256, 0, stream>>>(centers, feats, ood, targets, pseudo,
                                                      fall, cnt, cntT, Sacc);
  gemm_fused<<<dim3(NPAD / BN, NB / BM), 256, 0, stream>>>((const unsigned char*)fall, targets,
                                                           pseudo, cnt, Sacc, Pacc);
  finalize_k<<<1, 256, 0, stream>>>(Sacc, Pacc, targets, cntT, (float*)d_out);
}